// Round 1
// 103.419 us; speedup vs baseline: 1.0619x; 1.0619x over previous
//
#include <hip/hip_runtime.h>
#include <hip/hip_bf16.h>

// SimilarityPreserving loss, O(b*d^2) factorization (b=8192, d=128):
//   loss = (1/b^2) * sum_i 2*(1 - rho_i),  rho_i = C_i / sqrt(A_i*B_i)
//   A_i = xt_i^T Gt xt_i,  Gt = Yt_hat^T Yt_hat  (Yt_hat = row-normalized zyt)
//   B_i = xs_i^T Gs xs_i,  Gs = Ys_hat^T Ys_hat
//   C_i = xt_i^T M  xs_i,  M  = Yt_hat^T Ys_hat
// X normalization and temperature fold out of rho (scale invariance); eps
// never binds. Math verified R5/R6 (absmax 0.0).
//
// R8 (post-mortem of R7: top-5 dispatches are all harness poison fills at
// ~43us/78% HBM; our kernels are each <42us and the pipeline models at
// ~15-25us, so the remaining kernel-side slack is grid under-fill):
//  - quad_k: 128 -> 256 blocks (was using HALF the 256-CU chip). Block owns
//    32 rows; nt (d2-strip) loop split across wave pairs: wave = (rowgrp g,
//    nt-half h), 4 nt x 4 kk x 3 = 48 MFMA/wave; per-row A/B/C partials
//    combined across the two h-waves via 1 KB LDS, then one wave does
//    rho + block reduce + atomicAdd.
//  - prep: 256 -> 512 blocks (2/CU), 32 rows/chunk, 16 rows/thread: halves
//    the serial strided-load chain and doubles latency-hiding waves.
//  - gram_g / reduce_g unchanged (verified).

typedef __attribute__((ext_vector_type(8))) short short8;   // 8 bf16
typedef __attribute__((ext_vector_type(4))) float float4v;  // MFMA C/D

#define BSZ 8192
#define DIM 128
#define NP  64           // k-splits per gram (K=128 each)
#define INV_B2 1.4901161193847656e-08f  // 1/8192^2

__device__ __forceinline__ short f2bf(float x) {
    union { __hip_bfloat16 b; short s; } u;
    u.b = __float2bfloat16(x);
    return u.s;
}

// ---------------------------------------------------------------- stage 0
// prep: block (chunk, mat) normalizes 32 rows of one Y and writes them
// TRANSPOSED bf16 into YT[mat][d][8192]. Thread owns column d for 16 rows:
// loads are coalesced (256B/row-instr), transposed stores are per-thread
// contiguous 32 B. Norms: 64-lane shfl + 2-half LDS combine (once per row).
__global__ __launch_bounds__(256) void prep(
    const float* __restrict__ Yt, const float* __restrict__ Ys,
    short* __restrict__ YT, float* __restrict__ out)
{
    __shared__ float rsum[2][32];
    __shared__ float invn[32];

    const int tid   = threadIdx.x;
    const int lane  = tid & 63;
    const int wave  = tid >> 6;     // 0..3; wave&1 = d-half
    const int d     = tid & 127;
    const int khalf = tid >> 7;     // 0/1: row half (rows 0-15 / 16-31)
    const int chunk = blockIdx.x;   // 0..255 (32 rows each)
    const int mat   = blockIdx.y;   // 0..1
    const float* Y  = mat ? Ys : Yt;

    if (chunk == 0 && mat == 0 && tid == 0) out[0] = 0.f;

    float v[16];
    const float* base = Y + (size_t)(chunk * 32 + khalf * 16) * DIM + d;
    #pragma unroll
    for (int i = 0; i < 16; ++i) v[i] = base[(size_t)i * DIM];

    #pragma unroll
    for (int i = 0; i < 16; ++i) {
        float ss = v[i] * v[i];
        #pragma unroll
        for (int off = 1; off < 64; off <<= 1) ss += __shfl_xor(ss, off);
        if (lane == 0) rsum[wave & 1][khalf * 16 + i] = ss;
    }
    __syncthreads();
    if (tid < 32) {
        float s = rsum[0][tid] + rsum[1][tid];
        invn[tid] = (s > 0.f) ? rsqrtf(s) : 0.f;
    }
    __syncthreads();

    short* yt = YT + ((size_t)mat * 128 + d) * BSZ + chunk * 32 + khalf * 16;
    #pragma unroll
    for (int g = 0; g < 2; ++g) {
        short8 pk;
        #pragma unroll
        for (int j = 0; j < 8; ++j) {
            int i = g * 8 + j;
            pk[j] = f2bf(v[i] * invn[khalf * 16 + i]);
        }
        *(short8*)&yt[g * 8] = pk;
    }
}

// ---------------------------------------------------------------- stage 1
// Block (split, gram): fp32 partial G over k-rows [split*128, +128).
// 8 waves, wave = d1-strip. Fragments load straight from YT (contiguous 16B
// per lane; per instr 16 rows x 64 B segments). 32 MFMA/wave, no LDS.
__global__ __launch_bounds__(512) void gram_g(
    const short* __restrict__ YT, float* __restrict__ partial)
{
    const int tid  = threadIdx.x;
    const int lane = tid & 63;
    const int s1   = tid >> 6;    // wave = d1 strip 0..7
    const int q    = lane >> 4;
    const int l15  = lane & 15;
    const int split = blockIdx.x; // 0..NP-1
    const int gram  = blockIdx.y; // 0=Gt 1=Gs 2=M

    const short* Ta = (gram == 1) ? YT + (size_t)128 * BSZ : YT;  // Gs->Ys
    const short* Tb = (gram == 0) ? YT : YT + (size_t)128 * BSZ;  // Gt->Yt
    const int k0 = split * 128;

    float4v acc[8];
    #pragma unroll
    for (int s2 = 0; s2 < 8; ++s2) acc[s2] = (float4v){0.f, 0.f, 0.f, 0.f};

    #pragma unroll
    for (int kk = 0; kk < 4; ++kk) {
        const int ko = k0 + kk * 32 + q * 8;
        short8 fa = *(const short8*)&Ta[(size_t)(s1 * 16 + l15) * BSZ + ko];
        short8 fb[8];
        #pragma unroll
        for (int s2 = 0; s2 < 8; ++s2)
            fb[s2] = *(const short8*)&Tb[(size_t)(s2 * 16 + l15) * BSZ + ko];
        #pragma unroll
        for (int s2 = 0; s2 < 8; ++s2)
            acc[s2] = __builtin_amdgcn_mfma_f32_16x16x32_bf16(fa, fb[s2], acc[s2], 0, 0, 0);
    }

    // D tile: d1 = s1*16 + q*4 + r, d2 = s2*16 + l15.
    float* P = partial + ((size_t)(gram * NP + split) << 14);
    #pragma unroll
    for (int s2 = 0; s2 < 8; ++s2)
        #pragma unroll
        for (int r = 0; r < 4; ++r)
            P[((s1 * 16 + q * 4 + r) << 7) + s2 * 16 + l15] = acc[s2][r];
}

// ---------------------------------------------------------------- stage 2
// Sum NP partials -> Gb[g][d2][d1] bf16 (transposed so quad_k's B-fragments
// are contiguous 16B loads).
__global__ __launch_bounds__(256) void reduce_g(
    const float* __restrict__ partial, __hip_bfloat16* __restrict__ Gb)
{
    int o = blockIdx.x * 256 + threadIdx.x;   // < 3*16384
    int g = o >> 14, rem = o & 16383;
    float s = 0.f;
    for (int b = 0; b < NP; ++b)
        s += partial[((size_t)(g * NP + b) << 14) + rem];
    int d1 = rem >> 7, d2 = rem & 127;
    Gb[(g << 14) + (d2 << 7) + d1] = __float2bfloat16(s);
}

// ---------------------------------------------------------------- stage 3
// Per row i: Q = x^T G via MFMA, fold Q.x -> A,B,C; rho; atomicAdd loss.
// Raw fp32 X (normalization folds out of rho). 256 blocks x 4 waves.
// Block owns 32 rows: wave = (rowgrp g = wave&1 -> 16 rows, nt-half
// h = wave>>1 -> 4 of 8 d2-strips). Per-row A/B/C combined across the two
// h-waves in LDS, then wave 0 computes rho and block-reduces.
__global__ __launch_bounds__(256) void quad_k(
    const float* __restrict__ Xt, const float* __restrict__ Xs,
    const __hip_bfloat16* __restrict__ Gb, float* __restrict__ out)
{
    const int tid  = threadIdx.x;
    const int lane = tid & 63;
    const int wave = tid >> 6;
    const int q    = lane >> 4;
    const int l15  = lane & 15;
    const int g    = wave & 1;      // row group within block
    const int h    = wave >> 1;     // nt half
    const int rbase = blockIdx.x * 32 + g * 16;

    // A-frags: lane holds X[rbase+l15][kk*32+q*8 ..+8) as bf16
    short8 At[4], As[4];
    #pragma unroll
    for (int kk = 0; kk < 4; ++kk) {
        const float* pt = Xt + (size_t)(rbase + l15) * DIM + kk * 32 + q * 8;
        const float* ps = Xs + (size_t)(rbase + l15) * DIM + kk * 32 + q * 8;
        float4 t0 = *(const float4*)pt, t1 = *(const float4*)(pt + 4);
        float4 s0 = *(const float4*)ps, s1 = *(const float4*)(ps + 4);
        short8 a, b;
        a[0]=f2bf(t0.x); a[1]=f2bf(t0.y); a[2]=f2bf(t0.z); a[3]=f2bf(t0.w);
        a[4]=f2bf(t1.x); a[5]=f2bf(t1.y); a[6]=f2bf(t1.z); a[7]=f2bf(t1.w);
        b[0]=f2bf(s0.x); b[1]=f2bf(s0.y); b[2]=f2bf(s0.z); b[3]=f2bf(s0.w);
        b[4]=f2bf(s1.x); b[5]=f2bf(s1.y); b[6]=f2bf(s1.z); b[7]=f2bf(s1.w);
        At[kk] = a; As[kk] = b;
    }

    float fA[4] = {0,0,0,0}, fB[4] = {0,0,0,0}, fC[4] = {0,0,0,0};
    const short* G = (const short*)Gb;

    #pragma unroll
    for (int nti = 0; nti < 4; ++nti) {
        int d2 = (h * 4 + nti) * 16 + l15;
        float4v qt = {0.f,0.f,0.f,0.f}, qs = qt, qc = qt;
        #pragma unroll
        for (int kk = 0; kk < 4; ++kk) {
            int off = (d2 << 7) + kk * 32 + q * 8;
            short8 Bt = *(const short8*)&G[off];
            short8 Bs = *(const short8*)&G[16384 + off];
            short8 Bm = *(const short8*)&G[32768 + off];
            qt = __builtin_amdgcn_mfma_f32_16x16x32_bf16(At[kk], Bt, qt, 0, 0, 0);
            qs = __builtin_amdgcn_mfma_f32_16x16x32_bf16(As[kk], Bs, qs, 0, 0, 0);
            qc = __builtin_amdgcn_mfma_f32_16x16x32_bf16(At[kk], Bm, qc, 0, 0, 0);
        }
        // fold: D row = q*4+r, col = l15 -> Q[row][d2]; A += Q*x, etc.
        #pragma unroll
        for (int r = 0; r < 4; ++r) {
            int row = rbase + q * 4 + r;
            float xtv = Xt[(size_t)row * DIM + d2];
            float xsv = Xs[(size_t)row * DIM + d2];
            fA[r] += qt[r] * xtv;
            fB[r] += qs[r] * xsv;
            fC[r] += qc[r] * xsv;
        }
    }

    // 16-lane reduce per r -> per-row partials at l15==0; combine h-halves
    // via LDS. cmb[g][row][h*4 + {A,B,C}] (stride 8 floats, conflict-free).
    __shared__ float cmb[2][16][8];
    #pragma unroll
    for (int r = 0; r < 4; ++r) {
        float A = fA[r], B = fB[r], C = fC[r];
        #pragma unroll
        for (int off = 1; off < 16; off <<= 1) {
            A += __shfl_xor(A, off);
            B += __shfl_xor(B, off);
            C += __shfl_xor(C, off);
        }
        if (l15 == 0) {
            cmb[g][q * 4 + r][h * 4 + 0] = A;
            cmb[g][q * 4 + r][h * 4 + 1] = B;
            cmb[g][q * 4 + r][h * 4 + 2] = C;
        }
    }
    __syncthreads();

    if (wave == 0) {
        float wl = 0.f;
        if (tid < 32) {
            int gg = tid >> 4, row = tid & 15;
            float A = cmb[gg][row][0] + cmb[gg][row][4];
            float B = cmb[gg][row][1] + cmb[gg][row][5];
            float C = cmb[gg][row][2] + cmb[gg][row][6];
            wl = 2.f - 2.f * C * rsqrtf(A * B);
        }
        #pragma unroll
        for (int off = 1; off < 64; off <<= 1) wl += __shfl_xor(wl, off);
        if (tid == 0) atomicAdd(out, wl * INV_B2);
    }
}

// ---------------------------------------------------------------- launch
extern "C" void kernel_launch(void* const* d_in, const int* in_sizes, int n_in,
                              void* d_out, int out_size, void* d_ws, size_t ws_size,
                              hipStream_t stream) {
    const float* zxs = (const float*)d_in[0];
    const float* zys = (const float*)d_in[1];
    const float* zxt = (const float*)d_in[2];
    const float* zyt = (const float*)d_in[3];
    // d_in[4] = temperature: folds out of rho, unused.
    float* out = (float*)d_out;

    char* ws = (char*)d_ws;
    short* YT = (short*)ws;                                    // 2 x 128 x 8192 bf16 = 4 MB
    float* partial = (float*)(ws + (size_t)4 * 1024 * 1024);   // 3*NP*16384 fp32 = 12.6 MB
    __hip_bfloat16* Gb = (__hip_bfloat16*)(ws + (size_t)4 * 1024 * 1024
                                              + (size_t)3 * NP * 16384 * sizeof(float));

    prep    <<<dim3(256, 2), 256, 0, stream>>>(zyt, zys, YT, out);
    gram_g  <<<dim3(NP, 3),  512, 0, stream>>>(YT, partial);
    reduce_g<<<192,          256, 0, stream>>>(partial, Gb);
    quad_k  <<<256,          256, 0, stream>>>(zxt, zxs, Gb, out);
}